// Round 6
// baseline (236.399 us; speedup 1.0000x reference)
//
#include <hip/hip_runtime.h>
#include <hip/hip_fp16.h>

#define D_FEAT 128
#define MAX_CHUNK 1024

// Accumulate 4 halves (packed in a uint2) into a float4 accumulator.
__device__ __forceinline__ void acc8(float4& acc, const uint2 p) {
    const float2 lo = __half22float2(*(const __half2*)&p.x);
    const float2 hi = __half22float2(*(const __half2*)&p.y);
    acc.x += lo.x; acc.y += lo.y; acc.z += hi.x; acc.w += hi.y;
}

// ---------------------------------------------------------------------------
// Fused prep kernel.
//   Blocks [0, n4/256):            fp32 table -> fp16 SLICE-MAJOR table
//                                  tab[s][node][16cols], s = col/16. Each
//                                  slice is a contiguous 3.2 MB region.
//   Remaining blocks:              segment offsets from sorted macro ids.
__global__ __launch_bounds__(256)
void prep_kernel(const float* __restrict__ feat, __half* __restrict__ tab,
                 int n4, size_t slice_elems,
                 const int* __restrict__ mids, int n_gather,
                 int num_macro, int* __restrict__ offsets) {
    const int gid = blockIdx.x * blockDim.x + threadIdx.x;
    if (gid < n4) {
        // convert: one float4 (one column-quad) per thread
        const float4 v = ((const float4*)feat)[gid];
        const int node = gid >> 5;          // 32 quads per 128-wide row
        const int q    = gid & 31;
        const int s    = q >> 2;            // slice 0..7
        const int cc4  = (q & 3) << 2;      // column within slice
        const __half2 a = __floats2half2_rn(v.x, v.y);
        const __half2 b = __floats2half2_rn(v.z, v.w);
        uint2 o;
        o.x = *(const unsigned int*)&a;
        o.y = *(const unsigned int*)&b;
        *(uint2*)(tab + (size_t)s * slice_elems + (size_t)node * 16 + cc4) = o;
    } else {
        const int i = gid - n4;
        if (i >= n_gather) return;
        const int cur  = __builtin_nontemporal_load(&mids[i]);
        const int prev = (i == 0) ? -1 : __builtin_nontemporal_load(&mids[i - 1]);
        for (int m = prev + 1; m <= cur; ++m) offsets[m] = i;
        if (i == n_gather - 1) {
            for (int m = cur + 1; m <= num_macro; ++m) offsets[m] = n_gather;
        }
    }
}

// ---------------------------------------------------------------------------
// Pool kernel, XCD-sliced: blockIdx.x & 7 = column slice -> XCD (round-robin
// dispatch heuristic); each XCD touches only its contiguous 3.2 MB sub-table
// -> L2-resident. 4 waves/block, one macro node per wave, no LDS/barriers.
// Wave layout: lane = rowpos(16) x colq(4); indices loaded once per 64 rows
// (nontemporal, keeps L2 for the table) and distributed via __shfl.
__global__ __launch_bounds__(256)
void pool_mean_sliced_kernel(const __half* __restrict__ tab,
                             const int* __restrict__ nids,
                             const int* __restrict__ offsets,
                             float* __restrict__ out,
                             int num_macro, size_t slice_elems) {
    const int slice = blockIdx.x & 7;
    const int wave  = threadIdx.x >> 6;
    const int m     = (blockIdx.x >> 3) * 4 + wave;
    if (m >= num_macro) return;

    const int lane   = threadIdx.x & 63;
    const int rowpos = lane >> 2;        // 0..15
    const int colq   = lane & 3;         // 4 halves each -> 16 cols/slice

    const __half* base = tab + (size_t)slice * slice_elems;
    const int start = offsets[m];
    const int cnt   = offsets[m + 1] - start;

    float4 acc = make_float4(0.f, 0.f, 0.f, 0.f);

    for (int b0 = 0; b0 < cnt; b0 += 64) {
        const int rem = min(cnt - b0, 64);
        // one coalesced index load per 64 rows; clamped for tail lanes
        const int my = __builtin_nontemporal_load(
            &nids[start + b0 + ((lane < rem) ? lane : 0)]);

        for (int b = 0; b < rem; b += 32) {
            const int r0 = b + rowpos;
            const int r1 = b + 16 + rowpos;
            const int i0 = __shfl(my, (r0 < rem) ? r0 : 0, 64);
            const int i1 = __shfl(my, (r1 < rem) ? r1 : 0, 64);
            // two independent 8B gathers in flight
            const uint2 w0 = *(const uint2*)(base + (size_t)i0 * 16 + (colq << 2));
            const uint2 w1 = *(const uint2*)(base + (size_t)i1 * 16 + (colq << 2));
            if (r0 < rem) acc8(acc, w0);
            if (r1 < rem) acc8(acc, w1);
        }
    }

    // reduce over rowpos (lane bits 2..5)
    #pragma unroll
    for (int mask = 4; mask <= 32; mask <<= 1) {
        acc.x += __shfl_xor(acc.x, mask, 64);
        acc.y += __shfl_xor(acc.y, mask, 64);
        acc.z += __shfl_xor(acc.z, mask, 64);
        acc.w += __shfl_xor(acc.w, mask, 64);
    }

    if (lane < 4) {   // rowpos==0, colq=0..3 -> 64B contiguous store
        const float inv = (cnt > 0) ? (1.0f / (float)cnt) : 0.0f;
        float4 r = make_float4(acc.x * inv, acc.y * inv, acc.z * inv, acc.w * inv);
        *(float4*)(out + (size_t)m * D_FEAT + slice * 16 + (colq << 2)) = r;
    }
}

// ---------------------------------------------------------------------------
// Fallback (fp32 table, no shadow) — only if ws_size can't hold the fp16 table.
__global__ __launch_bounds__(256)
void pool_mean_fp32_kernel(const float* __restrict__ feat,
                           const int* __restrict__ nids,
                           const int* __restrict__ offsets,
                           float* __restrict__ out) {
    const int m    = blockIdx.x;
    const int tid  = threadIdx.x;
    const int g    = tid >> 5;
    const int c4   = (tid & 31) << 2;

    const int start = offsets[m];
    const int cnt   = offsets[m + 1] - start;

    __shared__ int   s_idx[MAX_CHUNK];
    __shared__ float red[8][D_FEAT];

    float4 acc = make_float4(0.f, 0.f, 0.f, 0.f);
    for (int base = 0; base < cnt; base += MAX_CHUNK) {
        const int chunk = min(cnt - base, MAX_CHUNK);
        for (int t = tid; t < chunk; t += 256) s_idx[t] = nids[start + base + t];
        __syncthreads();
        int r = g;
        for (; r + 24 < chunk; r += 32) {
            const float4 v0 = *(const float4*)(feat + (size_t)s_idx[r]      * D_FEAT + c4);
            const float4 v1 = *(const float4*)(feat + (size_t)s_idx[r + 8]  * D_FEAT + c4);
            const float4 v2 = *(const float4*)(feat + (size_t)s_idx[r + 16] * D_FEAT + c4);
            const float4 v3 = *(const float4*)(feat + (size_t)s_idx[r + 24] * D_FEAT + c4);
            acc.x += v0.x + v1.x + v2.x + v3.x;
            acc.y += v0.y + v1.y + v2.y + v3.y;
            acc.z += v0.z + v1.z + v2.z + v3.z;
            acc.w += v0.w + v1.w + v2.w + v3.w;
        }
        for (; r < chunk; r += 8) {
            const float4 v = *(const float4*)(feat + (size_t)s_idx[r] * D_FEAT + c4);
            acc.x += v.x; acc.y += v.y; acc.z += v.z; acc.w += v.w;
        }
        __syncthreads();
    }

    red[g][c4 + 0] = acc.x;
    red[g][c4 + 1] = acc.y;
    red[g][c4 + 2] = acc.z;
    red[g][c4 + 3] = acc.w;
    __syncthreads();

    if (tid < D_FEAT) {
        float s = 0.f;
        #pragma unroll
        for (int k = 0; k < 8; ++k) s += red[k][tid];
        const float inv = (cnt > 0) ? (1.0f / (float)cnt) : 0.0f;
        out[(size_t)m * D_FEAT + tid] = s * inv;
    }
}

extern "C" void kernel_launch(void* const* d_in, const int* in_sizes, int n_in,
                              void* d_out, int out_size, void* d_ws, size_t ws_size,
                              hipStream_t stream) {
    const float* feat = (const float*)d_in[0];   // [n_nodes, 128] fp32
    const int*   nids = (const int*)d_in[1];     // [n_gather] int32
    const int*   mids = (const int*)d_in[2];     // [n_gather] int32, sorted
    float*       out  = (float*)d_out;           // [num_macro, 128] fp32

    const int n_gather  = in_sizes[1];
    const int num_macro = out_size / D_FEAT;
    const int n_nodes   = in_sizes[0] / D_FEAT;

    // d_ws layout: [offsets: (num_macro+1) ints][align 256][fp16 slice-major table]
    int* offsets = (int*)d_ws;
    const size_t off_bytes    = ((size_t)(num_macro + 1) * sizeof(int) + 255) & ~(size_t)255;
    const size_t slice_elems  = (size_t)n_nodes * 16;            // halves per slice
    const size_t tab_bytes    = slice_elems * 8 * sizeof(__half);
    const bool   use_fp16     = (off_bytes + tab_bytes) <= ws_size;

    if (use_fp16) {
        __half* tab = (__half*)((char*)d_ws + off_bytes);
        const int n4 = n_nodes * (D_FEAT / 4);                   // convert threads
        const int total_threads = n4 + n_gather;
        prep_kernel<<<(total_threads + 255) / 256, 256, 0, stream>>>(
            feat, tab, n4, slice_elems, mids, n_gather, num_macro, offsets);
        const int nblocks = ((num_macro + 3) / 4) * 8;
        pool_mean_sliced_kernel<<<nblocks, 256, 0, stream>>>(
            tab, nids, offsets, out, num_macro, slice_elems);
    } else {
        prep_kernel<<<(n_gather + 255) / 256, 256, 0, stream>>>(
            feat, (__half*)nullptr, 0, 0, mids, n_gather, num_macro, offsets);
        pool_mean_fp32_kernel<<<num_macro, 256, 0, stream>>>(feat, nids, offsets, out);
    }
}